// Round 11
// baseline (1241.978 us; speedup 1.0000x reference)
//
#include <hip/hip_runtime.h>
#include <math.h>

#define BNUM 64
#define TNUM 512
#define NJ   17
#define CC   128
#define HIDC 64

#define RSQ 0.9999950000374997f  // 1/sqrt(1+1e-5)

typedef __attribute__((ext_vector_type(8))) short bf16x8;
typedef __attribute__((ext_vector_type(4))) float f32x4;

__device__ __forceinline__ float bf2f(unsigned short u) {
    union { unsigned int i; float f; } v; v.i = ((unsigned int)u) << 16; return v.f;
}
__device__ __forceinline__ unsigned short f2bf(float f) {
    union { float f; unsigned int i; } v; v.f = f;
    return (unsigned short)((v.i + 0x7FFF + ((v.i >> 16) & 1)) >> 16);
}
__device__ __forceinline__ void unpack8(const uint4 v, float* f) {
    f[0] = bf2f((unsigned short)(v.x & 0xFFFF)); f[1] = bf2f((unsigned short)(v.x >> 16));
    f[2] = bf2f((unsigned short)(v.y & 0xFFFF)); f[3] = bf2f((unsigned short)(v.y >> 16));
    f[4] = bf2f((unsigned short)(v.z & 0xFFFF)); f[5] = bf2f((unsigned short)(v.z >> 16));
    f[6] = bf2f((unsigned short)(v.w & 0xFFFF)); f[7] = bf2f((unsigned short)(v.w >> 16));
}
__device__ __forceinline__ uint4 pack8(const float* f) {
    uint4 v;
    v.x = (unsigned)f2bf(f[0]) | ((unsigned)f2bf(f[1]) << 16);
    v.y = (unsigned)f2bf(f[2]) | ((unsigned)f2bf(f[3]) << 16);
    v.z = (unsigned)f2bf(f[4]) | ((unsigned)f2bf(f[5]) << 16);
    v.w = (unsigned)f2bf(f[6]) | ((unsigned)f2bf(f[7]) << 16);
    return v;
}

constexpr unsigned ADJM[NJ] = {
    0x7u, 0xBu, 0x15u, 0xAu, 0x14u,
    0x8E0u, 0x1160u, 0x2A0u, 0x540u, 0x280u, 0x500u,
    0x3820u, 0x5840u, 0xA800u, 0x15000u, 0xA000u, 0x14000u
};
constexpr float DINV[NJ] = {
    0.5773502691896258f, 0.5773502691896258f, 0.5773502691896258f,
    0.7071067811865476f, 0.7071067811865476f,
    0.5f, 0.5f,
    0.5773502691896258f, 0.5773502691896258f,
    0.7071067811865476f, 0.7071067811865476f,
    0.5f, 0.5f,
    0.5773502691896258f, 0.5773502691896258f,
    0.7071067811865476f, 0.7071067811865476f
};

__global__ void k_fallback(float* out) { out[threadIdx.x] = 0.f; }

// pack conv weights (3 layers via grid.y): cw [2176][128][3] fp32 -> [oc][k*128+i] bf16
__global__ void k_prep_cwB(const float* __restrict__ cw0, const float* __restrict__ cw1,
                           const float* __restrict__ cw2, unsigned short* __restrict__ cwB) {
    const int idx = blockIdx.x * 256 + threadIdx.x;
    if (idx >= NJ * CC * 3 * CC) return;
    const float* cw = (blockIdx.y == 0) ? cw0 : (blockIdx.y == 1) ? cw1 : cw2;
    const int oc = idx / 384, kk = idx % 384;
    const int ktap = kk >> 7, i = kk & 127;
    cwB[(size_t)blockIdx.y * (NJ * CC * 3 * CC) + idx] =
        f2bf(cw[((size_t)oc * CC + i) * 3 + ktap]);
}
// merged small preps: rwB + gwB0 + gwB1 + gwB2 (one launch)
__global__ void k_prep_misc(const float* __restrict__ rw,
                            const float* __restrict__ gw0, const float* __restrict__ gw1,
                            const float* __restrict__ gw2,
                            unsigned short* __restrict__ rwB, unsigned short* __restrict__ gwB0,
                            unsigned short* __restrict__ gwB1, unsigned short* __restrict__ gwB2) {
    int idx = blockIdx.x * 256 + threadIdx.x;
    if (idx < NJ * CC * HIDC) { rwB[idx] = f2bf(rw[idx]); return; }
    idx -= NJ * CC * HIDC;
    if (idx < CC * HIDC) { const int o = idx / HIDC, i = idx % HIDC;
        gwB0[idx] = f2bf(gw0[i * CC + o]); return; }
    idx -= CC * HIDC;
    if (idx < CC * CC) { const int o = idx / CC, i = idx % CC;
        gwB1[idx] = f2bf(gw1[i * CC + o]); return; }
    idx -= CC * CC;
    if (idx < CC * CC) { const int o = idx / CC, i = idx % CC;
        gwB2[idx] = f2bf(gw2[i * CC + o]); return; }
}

// ---------------- fused MFMA GCN (unchanged from round 8/10) ----------------
template<int CIN>
__device__ __forceinline__ void gcn_mfma_body(
        const unsigned short* __restrict__ gwB,
        const float* __restrict__ gb,
        const float* __restrict__ bn1g, const float* __restrict__ bn1b,
        unsigned short* __restrict__ H1, unsigned short* lds,
        int bt0, int tid) {
    const int lane = tid & 63;
    const int wnt  = tid >> 6;
    const int rbase = lane & 15;
    const int g8    = (lane >> 4) * 8;

    f32x4 acc[17][2] = {};
#pragma unroll
    for (int ks = 0; ks < CIN / 32; ++ks) {
        bf16x8 bfr[2];
#pragma unroll
        for (int nt = 0; nt < 2; ++nt)
            bfr[nt] = *reinterpret_cast<const bf16x8*>(
                &gwB[(size_t)(wnt * 32 + nt * 16 + rbase) * CIN + ks * 32 + g8]);
#pragma unroll
        for (int mt = 0; mt < 17; ++mt) {
            const int rl = mt * 16 + rbase;
            const bf16x8 a = *reinterpret_cast<const bf16x8*>(
                &lds[(rl * CIN + ks * 32 + g8) ^ ((rl & 7) << 3)]);
            acc[mt][0] = __builtin_amdgcn_mfma_f32_16x16x32_bf16(a, bfr[0], acc[mt][0], 0, 0, 0);
            acc[mt][1] = __builtin_amdgcn_mfma_f32_16x16x32_bf16(a, bfr[1], acc[mt][1], 0, 0, 0);
        }
    }
    __syncthreads();

    const int rrow = (lane >> 4) * 4;
#pragma unroll
    for (int mt = 0; mt < 17; ++mt)
#pragma unroll
        for (int nt = 0; nt < 2; ++nt)
#pragma unroll
            for (int q = 0; q < 4; ++q) {
                const int r = mt * 16 + rrow + q;
                const int o = wnt * 32 + nt * 16 + rbase;
                lds[(r * 128 + o) ^ ((r & 7) << 3)] = f2bf(acc[mt][nt][q]);
            }
    __syncthreads();

    const int btl = tid >> 4;
    const int cg  = tid & 15;
    float s8[NJ][8];
#pragma unroll
    for (int n = 0; n < NJ; ++n) {
        const int r = btl * NJ + n;
        const uint4 raw = *reinterpret_cast<const uint4*>(
            &lds[(r * 128 + cg * 8) ^ ((r & 7) << 3)]);
        unpack8(raw, s8[n]);
    }
#pragma unroll
    for (int m = 0; m < NJ; ++m) {
        float ym[8] = {};
#pragma unroll
        for (int n = 0; n < NJ; ++n) {
            if (ADJM[m] & (1u << n)) {
#pragma unroll
                for (int j = 0; j < 8; ++j) ym[j] = fmaf(s8[n][j], DINV[n], ym[j]);
            }
        }
        const int ch0 = m * CC + cg * 8;
        const float4 g0 = *reinterpret_cast<const float4*>(&gb[ch0]);
        const float4 g1 = *reinterpret_cast<const float4*>(&gb[ch0 + 4]);
        const float4 a0 = *reinterpret_cast<const float4*>(&bn1g[ch0]);
        const float4 a1 = *reinterpret_cast<const float4*>(&bn1g[ch0 + 4]);
        const float4 c0 = *reinterpret_cast<const float4*>(&bn1b[ch0]);
        const float4 c1 = *reinterpret_cast<const float4*>(&bn1b[ch0 + 4]);
        const float gbv[8] = {g0.x, g0.y, g0.z, g0.w, g1.x, g1.y, g1.z, g1.w};
        const float sgv[8] = {a0.x, a0.y, a0.z, a0.w, a1.x, a1.y, a1.z, a1.w};
        const float sbv[8] = {c0.x, c0.y, c0.z, c0.w, c1.x, c1.y, c1.z, c1.w};
        float out8[8];
#pragma unroll
        for (int j = 0; j < 8; ++j) {
            const float y = fmaf(ym[j], DINV[m], gbv[j]);
            out8[j] = fmaxf(fmaf(y, sgv[j] * RSQ, sbv[j]), 0.f);
        }
        *reinterpret_cast<uint4*>(&H1[(size_t)(bt0 + btl) * (NJ * CC) + ch0]) = pack8(out8);
    }
}

__global__ __launch_bounds__(256, 1) void k_gcn_mfma(
        const unsigned short* __restrict__ X, const unsigned short* __restrict__ gwB,
        const float* __restrict__ gb,
        const float* __restrict__ bn1g, const float* __restrict__ bn1b,
        unsigned short* __restrict__ H1) {
    __shared__ __align__(16) unsigned short lds[272 * 128];
    const int bt0 = blockIdx.x * 16;
    const int tid = threadIdx.x;
    for (int c = tid; c < 272 * 16; c += 256) {
        const int rl = c >> 4, s8 = c & 15;
        const uint4 v = *reinterpret_cast<const uint4*>(
            &X[(size_t)(bt0 * NJ + rl) * CC + s8 * 8]);
        *reinterpret_cast<uint4*>(&lds[(rl * 128 + s8 * 8) ^ ((rl & 7) << 3)]) = v;
    }
    __syncthreads();
    gcn_mfma_body<CC>(gwB, gb, bn1g, bn1b, H1, lds, bt0, tid);
}

__global__ __launch_bounds__(256, 1) void k_gcn0_mfma(
        const float* __restrict__ x,
        const float* __restrict__ w_in, const float* __restrict__ b_in,
        const unsigned short* __restrict__ gwB,
        const float* __restrict__ gb,
        const float* __restrict__ bn1g, const float* __restrict__ bn1b,
        unsigned short* __restrict__ H1) {
    __shared__ __align__(16) unsigned short lds[272 * 128];
    const int bt0 = blockIdx.x * 16;
    const int tid = threadIdx.x;
    for (int c = tid; c < 272 * 8; c += 256) {
        const int rl = c >> 3, i8 = c & 7;
        const int bt = bt0 + rl / NJ, n = rl % NJ;
        const float* xb = &x[(size_t)bt * (NJ * 3) + n * 3];
        const float x0 = xb[0], x1 = xb[1], x2 = xb[2];
        unsigned short tmp[8];
#pragma unroll
        for (int jj = 0; jj < 8; ++jj) {
            const int i = i8 * 8 + jj;
            tmp[jj] = f2bf(fmaf(x2, w_in[i * 3 + 2],
                           fmaf(x1, w_in[i * 3 + 1],
                           fmaf(x0, w_in[i * 3 + 0], b_in[i]))));
        }
        *reinterpret_cast<uint4*>(&lds[(rl * HIDC + i8 * 8) ^ ((rl & 7) << 3)]) =
            *reinterpret_cast<uint4*>(tmp);
    }
    __syncthreads();
    gcn_mfma_body<HIDC>(gwB, gb, bn1g, bn1b, H1, lds, bt0, tid);
}

// ------- persistent-t, double-buffered MFMA temporal conv + BN + ReLU + res [+pool]
// Block = (joint n, batch b); loops 8 t-tiles of 64 rows. Global->reg loads for
// tile k+1 issued before computing tile k (T14 issue-early/write-late); one
// barrier per tile. POOL=1: no OUT store; per-block pooled slice plain-stored.
template<int RES_MODE, int POOL>
__global__ __launch_bounds__(256) void k_tconv_mfma(
        const unsigned short* __restrict__ H1, const unsigned short* __restrict__ cwB,
        const float* __restrict__ cb,
        const float* __restrict__ bn2g, const float* __restrict__ bn2b,
        const float* __restrict__ RSRC,
        const float* __restrict__ w_in, const float* __restrict__ b_in,
        const unsigned short* __restrict__ rwB, const float* __restrict__ rb,
        const float* __restrict__ rg, const float* __restrict__ rbb,
        unsigned short* __restrict__ OUT, float* __restrict__ pooled) {
    __shared__ __align__(16) unsigned short xin[2][66 * 128];
    __shared__ __align__(16) unsigned short h0s[RES_MODE ? 2 : 1][RES_MODE ? 64 * 64 : 8];

    const int n   = blockIdx.x;
    const int b   = blockIdx.y;
    const int tid = threadIdx.x;
    const int lane = tid & 63;
    const int wnt  = tid >> 6;

    uint4 sreg[5];
    float hx[2][3];

    auto LOADT = [&](int it) {
        const int t0 = it * 64;
#pragma unroll
        for (int j = 0; j < 5; ++j) {
            const int c = tid + 256 * j;
            if (c < 66 * 16) {
                const int row = c >> 4, slot = c & 15;
                const int ti = t0 - 1 + row;
                uint4 v = {0u, 0u, 0u, 0u};
                if (ti >= 0 && ti < TNUM)
                    v = *reinterpret_cast<const uint4*>(
                            &H1[(((size_t)b * TNUM + ti) * NJ + n) * CC + slot * 8]);
                sreg[j] = v;
            }
        }
    };
    auto WRITET = [&](int buf) {
#pragma unroll
        for (int j = 0; j < 5; ++j) {
            const int c = tid + 256 * j;
            if (c < 66 * 16) {
                const int row = c >> 4, slot = c & 15;
                *reinterpret_cast<uint4*>(&xin[buf][(row * 128 + slot * 8) ^ ((row & 7) << 3)]) = sreg[j];
            }
        }
    };
    auto LOADH = [&](int it) {
        if constexpr (RES_MODE == 1) {
            const int t0 = it * 64;
#pragma unroll
            for (int j = 0; j < 2; ++j) {
                const int c = tid + 256 * j;
                const int r = c >> 3;
                const float* xb = &RSRC[((size_t)b * TNUM + t0 + r) * (NJ * 3) + n * 3];
                hx[j][0] = xb[0]; hx[j][1] = xb[1]; hx[j][2] = xb[2];
            }
        }
    };
    auto WRITEH = [&](int buf) {
        if constexpr (RES_MODE == 1) {
#pragma unroll
            for (int j = 0; j < 2; ++j) {
                const int c = tid + 256 * j;
                const int r = c >> 3, i8 = c & 7;
                float f[8];
#pragma unroll
                for (int jj = 0; jj < 8; ++jj) {
                    const int i = i8 * 8 + jj;
                    f[jj] = fmaf(hx[j][2], w_in[i * 3 + 2],
                            fmaf(hx[j][1], w_in[i * 3 + 1],
                            fmaf(hx[j][0], w_in[i * 3 + 0], b_in[i])));
                }
                *reinterpret_cast<uint4*>(&h0s[buf][(r * 64 + i8 * 8) ^ ((r & 7) << 3)]) = pack8(f);
            }
        }
    };

    const int rbase = lane & 15;
    const int g8    = (lane >> 4) * 8;
    const int rrow  = (lane >> 4) * 4;

    // hoist per-channel constants (2 cols per thread)
    float s2[2], bb2v[2], cbov[2], rsv[2], rshv[2], rbcv[2];
#pragma unroll
    for (int nt = 0; nt < 2; ++nt) {
        const int ch = n * CC + wnt * 32 + nt * 16 + rbase;
        s2[nt] = bn2g[ch] * RSQ; bb2v[nt] = bn2b[ch]; cbov[nt] = cb[ch];
        if constexpr (RES_MODE == 1) { rsv[nt] = rg[ch] * RSQ; rshv[nt] = rbb[ch]; rbcv[nt] = rb[ch]; }
        else { rsv[nt] = rshv[nt] = rbcv[nt] = 0.f; }
    }

    float pacc[2] = {0.f, 0.f};

    LOADT(0); LOADH(0);
    WRITET(0); WRITEH(0);
    LOADT(1); LOADH(1);
    __syncthreads();

    for (int it = 0; it < 8; ++it) {
        const int cur = it & 1, nxt = cur ^ 1;
        const int t0 = it * 64;

        f32x4 acc[4][2] = {};
        for (int ks = 0; ks < 12; ++ks) {
            const int ktap = ks >> 2;
            const int ib   = (ks & 3) * 32 + g8;
            bf16x8 a[4];
#pragma unroll
            for (int m = 0; m < 4; ++m) {
                const int rl = m * 16 + rbase + ktap;
                a[m] = *reinterpret_cast<const bf16x8*>(
                           &xin[cur][(rl * 128 + ib) ^ ((rl & 7) << 3)]);
            }
#pragma unroll
            for (int nt = 0; nt < 2; ++nt) {
                const int o = wnt * 32 + nt * 16 + rbase;
                const bf16x8 bf = *reinterpret_cast<const bf16x8*>(
                    &cwB[(size_t)(n * CC + o) * 384 + ks * 32 + g8]);
#pragma unroll
                for (int m = 0; m < 4; ++m)
                    acc[m][nt] = __builtin_amdgcn_mfma_f32_16x16x32_bf16(a[m], bf, acc[m][nt], 0, 0, 0);
            }
        }

        f32x4 accr[4][2] = {};
        if constexpr (RES_MODE == 1) {
            for (int ks = 0; ks < 2; ++ks) {
                const int ib = ks * 32 + g8;
                bf16x8 a[4];
#pragma unroll
                for (int m = 0; m < 4; ++m) {
                    const int rl = m * 16 + rbase;
                    a[m] = *reinterpret_cast<const bf16x8*>(
                               &h0s[cur][(rl * 64 + ib) ^ ((rl & 7) << 3)]);
                }
#pragma unroll
                for (int nt = 0; nt < 2; ++nt) {
                    const int o = wnt * 32 + nt * 16 + rbase;
                    const bf16x8 bf = *reinterpret_cast<const bf16x8*>(
                        &rwB[(size_t)(n * CC + o) * HIDC + ib]);
#pragma unroll
                    for (int m = 0; m < 4; ++m)
                        accr[m][nt] = __builtin_amdgcn_mfma_f32_16x16x32_bf16(a[m], bf, accr[m][nt], 0, 0, 0);
                }
            }
        }

        // epilogue: direct global (2B stores/loads were proven non-limiting)
#pragma unroll
        for (int nt = 0; nt < 2; ++nt) {
            const int o = wnt * 32 + nt * 16 + rbase;
#pragma unroll
            for (int m = 0; m < 4; ++m) {
#pragma unroll
                for (int q = 0; q < 4; ++q) {
                    const int r = m * 16 + rrow + q;
                    const size_t oi = (((size_t)b * TNUM + t0 + r) * NJ + n) * CC + o;
                    float v = fmaxf(fmaf(acc[m][nt][q] + cbov[nt], s2[nt], bb2v[nt]), 0.f);
                    if constexpr (RES_MODE == 1) v += fmaf(accr[m][nt][q] + rbcv[nt], rsv[nt], rshv[nt]);
                    else                         v += bf2f(OUT[oi]);
                    if constexpr (POOL == 1) pacc[nt] += v;
                    else                     OUT[oi] = f2bf(v);
                }
            }
        }

        if (it < 7) { WRITET(nxt); WRITEH(nxt); }
        if (it < 6) { LOADT(it + 2); LOADH(it + 2); }
        __syncthreads();
    }

    if constexpr (POOL == 1) {
#pragma unroll
        for (int nt = 0; nt < 2; ++nt) {
            pacc[nt] += __shfl_xor(pacc[nt], 16);
            pacc[nt] += __shfl_xor(pacc[nt], 32);
        }
        if ((lane >> 4) == 0) {
#pragma unroll
            for (int nt = 0; nt < 2; ++nt)
                pooled[((size_t)b * NJ + n) * CC + wnt * 32 + nt * 16 + rbase] =
                    pacc[nt] * (1.0f / TNUM);
        }
    }
}

// MLP head: 2176 -> 128 -> 64 -> 1, relu/relu/sigmoid
__global__ __launch_bounds__(128) void k_mlp(const float* __restrict__ P,
        const float* __restrict__ w1, const float* __restrict__ b1,
        const float* __restrict__ w2, const float* __restrict__ b2,
        const float* __restrict__ w3, const float* __restrict__ b3,
        float* __restrict__ out) {
    __shared__ float h1[128];
    __shared__ float h2[64];
    const int b = blockIdx.x, tid = threadIdx.x;
    const float* pr = P + (size_t)b * (NJ * CC);
    float acc = b1[tid];
    for (int i = 0; i < NJ * CC; ++i) acc = fmaf(pr[i], w1[i * 128 + tid], acc);
    h1[tid] = fmaxf(acc, 0.f);
    __syncthreads();
    if (tid < 64) {
        float a2 = b2[tid];
#pragma unroll 4
        for (int i = 0; i < 128; ++i) a2 = fmaf(h1[i], w2[i * 64 + tid], a2);
        h2[tid] = fmaxf(a2, 0.f);
    }
    __syncthreads();
    if (tid == 0) {
        float a3 = b3[0];
#pragma unroll 4
        for (int i = 0; i < 64; ++i) a3 = fmaf(h2[i], w3[i], a3);
        out[b] = 1.f / (1.f + expf(-a3));
    }
}

extern "C" void kernel_launch(void* const* d_in, const int* in_sizes, int n_in,
                              void* d_out, int out_size, void* d_ws, size_t ws_size,
                              hipStream_t stream) {
    const float* x    = (const float*)d_in[0];
    const float* w_in = (const float*)d_in[1];
    const float* b_in = (const float*)d_in[2];
    const float *gw[3], *gb[3], *bn1g[3], *bn1b[3], *cw[3], *cb[3], *bn2g[3], *bn2b[3];
    for (int l = 0; l < 3; ++l) {
        const int base = 3 + l * 8;
        gw[l]   = (const float*)d_in[base + 0];
        gb[l]   = (const float*)d_in[base + 1];
        bn1g[l] = (const float*)d_in[base + 2];
        bn1b[l] = (const float*)d_in[base + 3];
        cw[l]   = (const float*)d_in[base + 4];
        cb[l]   = (const float*)d_in[base + 5];
        bn2g[l] = (const float*)d_in[base + 6];
        bn2b[l] = (const float*)d_in[base + 7];
    }
    const float* rw0  = (const float*)d_in[27];
    const float* rb0  = (const float*)d_in[28];
    const float* rg0  = (const float*)d_in[29];
    const float* rbb0 = (const float*)d_in[30];
    const float* w1   = (const float*)d_in[31];
    const float* b1   = (const float*)d_in[32];
    const float* w2   = (const float*)d_in[33];
    const float* b2   = (const float*)d_in[34];
    const float* w3   = (const float*)d_in[35];
    const float* b3   = (const float*)d_in[36];

    const size_t CWB    = (size_t)NJ * CC * 3 * CC;
    const size_t RWB    = (size_t)NJ * CC * HIDC;
    const size_t GWB128 = (size_t)CC * CC;
    const size_t GWB64  = (size_t)CC * HIDC;
    const size_t ACT_B  = (size_t)TNUM * NJ * CC;
    const size_t POOLED = (size_t)BNUM * NJ * CC;
    const size_t fixedB = (3 * CWB + RWB + 2 * GWB128 + GWB64) * sizeof(unsigned short)
                        + POOLED * sizeof(float);

    int chunk = 0;
    for (int c = BNUM; c >= 1; c >>= 1) {
        const size_t need = fixedB + 2 * (size_t)c * ACT_B * sizeof(unsigned short);
        if (need <= ws_size) { chunk = c; break; }
    }
    if (chunk == 0) {
        k_fallback<<<1, 64, 0, stream>>>((float*)d_out);
        return;
    }

    unsigned short* cwB0 = (unsigned short*)d_ws;
    unsigned short* cwB1 = cwB0 + CWB;
    unsigned short* cwB2 = cwB1 + CWB;
    unsigned short* rwB  = cwB2 + CWB;
    unsigned short* gwB0 = rwB + RWB;
    unsigned short* gwB1 = gwB0 + GWB64;
    unsigned short* gwB2 = gwB1 + GWB128;
    float* pooled = (float*)(gwB2 + GWB128);
    unsigned short* bufA = (unsigned short*)(pooled + POOLED);
    unsigned short* bufB = bufA + (size_t)chunk * ACT_B;

    dim3 pgrid((int)((CWB + 255) / 256), 3, 1);
    k_prep_cwB<<<pgrid, 256, 0, stream>>>(cw[0], cw[1], cw[2], cwB0);
    const size_t MISC = RWB + GWB64 + 2 * GWB128;
    k_prep_misc<<<(int)((MISC + 255) / 256), 256, 0, stream>>>(
        rw0, gw[0], gw[1], gw[2], rwB, gwB0, gwB1, gwB2);

    for (int b0 = 0; b0 < BNUM; b0 += chunk) {
        const float* xc = x + (size_t)b0 * TNUM * NJ * 3;
        const int GB = chunk * TNUM / 16;
        const dim3 tgrid(NJ, chunk);
        float* pc = pooled + (size_t)b0 * NJ * CC;

        k_gcn0_mfma<<<GB, 256, 0, stream>>>(xc, w_in, b_in, gwB0,
                                            gb[0], bn1g[0], bn1b[0], bufA);
        k_tconv_mfma<1, 0><<<tgrid, 256, 0, stream>>>(bufA, cwB0, cb[0], bn2g[0], bn2b[0],
                                                      xc, w_in, b_in, rwB, rb0, rg0, rbb0,
                                                      bufB, nullptr);
        k_gcn_mfma<<<GB, 256, 0, stream>>>(bufB, gwB1, gb[1], bn1g[1], bn1b[1], bufA);
        k_tconv_mfma<0, 0><<<tgrid, 256, 0, stream>>>(bufA, cwB1, cb[1], bn2g[1], bn2b[1],
                                                      nullptr, w_in, b_in, nullptr, nullptr, nullptr, nullptr,
                                                      bufB, nullptr);
        k_gcn_mfma<<<GB, 256, 0, stream>>>(bufB, gwB2, gb[2], bn1g[2], bn1b[2], bufA);
        k_tconv_mfma<0, 1><<<tgrid, 256, 0, stream>>>(bufA, cwB2, cb[2], bn2g[2], bn2b[2],
                                                      nullptr, w_in, b_in, nullptr, nullptr, nullptr, nullptr,
                                                      bufB, pc);
    }

    k_mlp<<<BNUM, 128, 0, stream>>>(pooled, w1, b1, w2, b2, w3, b3, (float*)d_out);
}

// Round 12
// 948.106 us; speedup vs baseline: 1.3100x; 1.3100x over previous
//
#include <hip/hip_runtime.h>
#include <math.h>

#define BNUM 64
#define TNUM 512
#define NJ   17
#define CC   128
#define HIDC 64

#define RSQ 0.9999950000374997f  // 1/sqrt(1+1e-5)

typedef __attribute__((ext_vector_type(8))) short bf16x8;
typedef __attribute__((ext_vector_type(4))) float f32x4;

__device__ __forceinline__ float bf2f(unsigned short u) {
    union { unsigned int i; float f; } v; v.i = ((unsigned int)u) << 16; return v.f;
}
__device__ __forceinline__ unsigned short f2bf(float f) {
    union { float f; unsigned int i; } v; v.f = f;
    return (unsigned short)((v.i + 0x7FFF + ((v.i >> 16) & 1)) >> 16);
}
__device__ __forceinline__ void unpack8(const uint4 v, float* f) {
    f[0] = bf2f((unsigned short)(v.x & 0xFFFF)); f[1] = bf2f((unsigned short)(v.x >> 16));
    f[2] = bf2f((unsigned short)(v.y & 0xFFFF)); f[3] = bf2f((unsigned short)(v.y >> 16));
    f[4] = bf2f((unsigned short)(v.z & 0xFFFF)); f[5] = bf2f((unsigned short)(v.z >> 16));
    f[6] = bf2f((unsigned short)(v.w & 0xFFFF)); f[7] = bf2f((unsigned short)(v.w >> 16));
}
__device__ __forceinline__ uint4 pack8(const float* f) {
    uint4 v;
    v.x = (unsigned)f2bf(f[0]) | ((unsigned)f2bf(f[1]) << 16);
    v.y = (unsigned)f2bf(f[2]) | ((unsigned)f2bf(f[3]) << 16);
    v.z = (unsigned)f2bf(f[4]) | ((unsigned)f2bf(f[5]) << 16);
    v.w = (unsigned)f2bf(f[6]) | ((unsigned)f2bf(f[7]) << 16);
    return v;
}

constexpr unsigned ADJM[NJ] = {
    0x7u, 0xBu, 0x15u, 0xAu, 0x14u,
    0x8E0u, 0x1160u, 0x2A0u, 0x540u, 0x280u, 0x500u,
    0x3820u, 0x5840u, 0xA800u, 0x15000u, 0xA000u, 0x14000u
};
constexpr float DINV[NJ] = {
    0.5773502691896258f, 0.5773502691896258f, 0.5773502691896258f,
    0.7071067811865476f, 0.7071067811865476f,
    0.5f, 0.5f,
    0.5773502691896258f, 0.5773502691896258f,
    0.7071067811865476f, 0.7071067811865476f,
    0.5f, 0.5f,
    0.5773502691896258f, 0.5773502691896258f,
    0.7071067811865476f, 0.7071067811865476f
};

__global__ void k_fallback(float* out) { out[threadIdx.x] = 0.f; }
__global__ void k_zero(float* p, int n) {
    const int i = blockIdx.x * 256 + threadIdx.x;
    if (i < n) p[i] = 0.f;
}

// pack conv weights (3 layers via grid.y): cw [2176][128][3] fp32 -> [oc][k*128+i] bf16
__global__ void k_prep_cwB(const float* __restrict__ cw0, const float* __restrict__ cw1,
                           const float* __restrict__ cw2, unsigned short* __restrict__ cwB) {
    const int idx = blockIdx.x * 256 + threadIdx.x;
    if (idx >= NJ * CC * 3 * CC) return;
    const float* cw = (blockIdx.y == 0) ? cw0 : (blockIdx.y == 1) ? cw1 : cw2;
    const int oc = idx / 384, kk = idx % 384;
    const int ktap = kk >> 7, i = kk & 127;
    cwB[(size_t)blockIdx.y * (NJ * CC * 3 * CC) + idx] =
        f2bf(cw[((size_t)oc * CC + i) * 3 + ktap]);
}
// merged small preps: rwB + gwB0 + gwB1 + gwB2 (one launch)
__global__ void k_prep_misc(const float* __restrict__ rw,
                            const float* __restrict__ gw0, const float* __restrict__ gw1,
                            const float* __restrict__ gw2,
                            unsigned short* __restrict__ rwB, unsigned short* __restrict__ gwB0,
                            unsigned short* __restrict__ gwB1, unsigned short* __restrict__ gwB2) {
    int idx = blockIdx.x * 256 + threadIdx.x;
    if (idx < NJ * CC * HIDC) { rwB[idx] = f2bf(rw[idx]); return; }
    idx -= NJ * CC * HIDC;
    if (idx < CC * HIDC) { const int o = idx / HIDC, i = idx % HIDC;
        gwB0[idx] = f2bf(gw0[i * CC + o]); return; }
    idx -= CC * HIDC;
    if (idx < CC * CC) { const int o = idx / CC, i = idx % CC;
        gwB1[idx] = f2bf(gw1[i * CC + o]); return; }
    idx -= CC * CC;
    if (idx < CC * CC) { const int o = idx / CC, i = idx % CC;
        gwB2[idx] = f2bf(gw2[i * CC + o]); return; }
}

// ---------------- fused MFMA GCN, joint-major tiles + register adjacency mix --
// Rows: rl = n*16 + btl (16 bt per block, 17 M-tiles; tile mt = joint mt).
// After the K-loop each wave's acc[n][...] holds S for ALL joints at matching
// (btl, oc) lane positions -> adjacency mix is pure register math; BN+ReLU and
// store go straight from registers. One barrier total (after A-stage).
template<int CIN>
__device__ __forceinline__ void gcn_mfma_body(
        const unsigned short* __restrict__ gwB,
        const float* __restrict__ gb,
        const float* __restrict__ bn1g, const float* __restrict__ bn1b,
        unsigned short* __restrict__ H1, unsigned short* lds,
        int bt0, int tid) {
    const int lane = tid & 63;
    const int wnt  = tid >> 6;
    const int rbase = lane & 15;        // btl within tile
    const int g8    = (lane >> 4) * 8;
    const int rrow  = (lane >> 4) * 4;  // C/D row group

    f32x4 acc[17][2] = {};
#pragma unroll
    for (int ks = 0; ks < CIN / 32; ++ks) {
        bf16x8 bfr[2];
#pragma unroll
        for (int nt = 0; nt < 2; ++nt)
            bfr[nt] = *reinterpret_cast<const bf16x8*>(
                &gwB[(size_t)(wnt * 32 + nt * 16 + rbase) * CIN + ks * 32 + g8]);
#pragma unroll
        for (int mt = 0; mt < 17; ++mt) {
            const int rl = mt * 16 + rbase;
            const bf16x8 a = *reinterpret_cast<const bf16x8*>(
                &lds[(rl * CIN + ks * 32 + g8) ^ ((rl & 7) << 3)]);
            acc[mt][0] = __builtin_amdgcn_mfma_f32_16x16x32_bf16(a, bfr[0], acc[mt][0], 0, 0, 0);
            acc[mt][1] = __builtin_amdgcn_mfma_f32_16x16x32_bf16(a, bfr[1], acc[mt][1], 0, 0, 0);
        }
    }

    // premultiply S[n] by DINV[n]
#pragma unroll
    for (int n = 0; n < NJ; ++n)
#pragma unroll
        for (int nt = 0; nt < 2; ++nt)
#pragma unroll
            for (int q = 0; q < 4; ++q)
                acc[n][nt][q] *= DINV[n];

    // register adjacency mix + BN + ReLU + direct store
#pragma unroll
    for (int m = 0; m < NJ; ++m) {
        float ym[2][4] = {};
#pragma unroll
        for (int n = 0; n < NJ; ++n) {
            if (ADJM[m] & (1u << n)) {
#pragma unroll
                for (int nt = 0; nt < 2; ++nt)
#pragma unroll
                    for (int q = 0; q < 4; ++q)
                        ym[nt][q] += acc[n][nt][q];
            }
        }
#pragma unroll
        for (int nt = 0; nt < 2; ++nt) {
            const int o  = wnt * 32 + nt * 16 + rbase;
            const int ch = m * CC + o;
            const float sg = bn1g[ch] * RSQ, sb = bn1b[ch], gbo = gb[ch];
#pragma unroll
            for (int q = 0; q < 4; ++q) {
                const int btl = rrow + q;
                const float y = fmaf(ym[nt][q], DINV[m], gbo);
                H1[((size_t)(bt0 + btl) * NJ + m) * CC + o] =
                    f2bf(fmaxf(fmaf(y, sg, sb), 0.f));
            }
        }
    }
}

__global__ __launch_bounds__(256, 1) void k_gcn_mfma(
        const unsigned short* __restrict__ X, const unsigned short* __restrict__ gwB,
        const float* __restrict__ gb,
        const float* __restrict__ bn1g, const float* __restrict__ bn1b,
        unsigned short* __restrict__ H1) {
    __shared__ __align__(16) unsigned short lds[272 * 128];
    const int bt0 = blockIdx.x * 16;
    const int tid = threadIdx.x;
    for (int c = tid; c < 272 * 16; c += 256) {
        const int rl = c >> 4, s8 = c & 15;
        const int n = rl >> 4, btl = rl & 15;
        const uint4 v = *reinterpret_cast<const uint4*>(
            &X[((size_t)(bt0 + btl) * NJ + n) * CC + s8 * 8]);
        *reinterpret_cast<uint4*>(&lds[(rl * 128 + s8 * 8) ^ ((rl & 7) << 3)]) = v;
    }
    __syncthreads();
    gcn_mfma_body<CC>(gwB, gb, bn1g, bn1b, H1, lds, bt0, tid);
}

__global__ __launch_bounds__(256, 1) void k_gcn0_mfma(
        const float* __restrict__ x,
        const float* __restrict__ w_in, const float* __restrict__ b_in,
        const unsigned short* __restrict__ gwB,
        const float* __restrict__ gb,
        const float* __restrict__ bn1g, const float* __restrict__ bn1b,
        unsigned short* __restrict__ H1) {
    __shared__ __align__(16) unsigned short lds[272 * 64];
    const int bt0 = blockIdx.x * 16;
    const int tid = threadIdx.x;
    for (int c = tid; c < 272 * 8; c += 256) {
        const int rl = c >> 3, i8 = c & 7;
        const int n = rl >> 4, btl = rl & 15;
        const float* xb = &x[(size_t)(bt0 + btl) * (NJ * 3) + n * 3];
        const float x0 = xb[0], x1 = xb[1], x2 = xb[2];
        unsigned short tmp[8];
#pragma unroll
        for (int jj = 0; jj < 8; ++jj) {
            const int i = i8 * 8 + jj;
            tmp[jj] = f2bf(fmaf(x2, w_in[i * 3 + 2],
                           fmaf(x1, w_in[i * 3 + 1],
                           fmaf(x0, w_in[i * 3 + 0], b_in[i]))));
        }
        *reinterpret_cast<uint4*>(&lds[(rl * HIDC + i8 * 8) ^ ((rl & 7) << 3)]) =
            *reinterpret_cast<uint4*>(tmp);
    }
    __syncthreads();
    gcn_mfma_body<HIDC>(gwB, gb, bn1g, bn1b, H1, lds, bt0, tid);
}

// ---------------- MFMA grouped temporal conv (R10-proven structure) ----------
template<int RES_MODE, int POOL>
__global__ __launch_bounds__(256) void k_tconv_mfma(
        const unsigned short* __restrict__ H1, const unsigned short* __restrict__ cwB,
        const float* __restrict__ cb,
        const float* __restrict__ bn2g, const float* __restrict__ bn2b,
        const float* __restrict__ RSRC,
        const float* __restrict__ w_in, const float* __restrict__ b_in,
        const unsigned short* __restrict__ rwB, const float* __restrict__ rb,
        const float* __restrict__ rg, const float* __restrict__ rbb,
        unsigned short* __restrict__ OUT, float* __restrict__ pooled) {
    __shared__ __align__(16) unsigned short xin[66 * 128];
    __shared__ __align__(16) unsigned short h0s[RES_MODE ? 64 * 64 : 8];

    const int t0  = blockIdx.x * 64;
    const int n   = blockIdx.y;
    const int b   = blockIdx.z;
    const int tid = threadIdx.x;
    const int lane = tid & 63;
    const int wnt  = tid >> 6;

    for (int c = tid; c < 66 * 16; c += 256) {
        const int row = c >> 4, slot = c & 15;
        const int ti = t0 - 1 + row;
        uint4 v = {0u, 0u, 0u, 0u};
        if (ti >= 0 && ti < TNUM)
            v = *reinterpret_cast<const uint4*>(
                    &H1[(((size_t)b * TNUM + ti) * NJ + n) * CC + slot * 8]);
        const int u = (row * 128 + slot * 8) ^ ((row & 7) << 3);
        *reinterpret_cast<uint4*>(&xin[u]) = v;
    }
    if constexpr (RES_MODE == 1) {
        for (int c = tid; c < 64 * 8; c += 256) {
            const int r = c >> 3, i8 = c & 7;
            const float* xb = &RSRC[((size_t)b * TNUM + t0 + r) * (NJ * 3) + n * 3];
            const float x0 = xb[0], x1 = xb[1], x2 = xb[2];
            unsigned short tmp[8];
#pragma unroll
            for (int j = 0; j < 8; ++j) {
                const int i = i8 * 8 + j;
                tmp[j] = f2bf(fmaf(x2, w_in[i * 3 + 2],
                              fmaf(x1, w_in[i * 3 + 1],
                              fmaf(x0, w_in[i * 3 + 0], b_in[i]))));
            }
            const int u = (r * 64 + i8 * 8) ^ ((r & 7) << 3);
            *reinterpret_cast<uint4*>(&h0s[u]) = *reinterpret_cast<uint4*>(tmp);
        }
    }
    __syncthreads();

    const int rbase = lane & 15;
    const int g8    = (lane >> 4) * 8;

    f32x4 acc[4][2] = {};
#pragma unroll
    for (int ks = 0; ks < 12; ++ks) {
        const int ktap = ks >> 2;
        const int ib   = (ks & 3) * 32 + g8;
        bf16x8 a[4];
#pragma unroll
        for (int m = 0; m < 4; ++m) {
            const int rl = m * 16 + rbase + ktap;
            a[m] = *reinterpret_cast<const bf16x8*>(
                       &xin[(rl * 128 + ib) ^ ((rl & 7) << 3)]);
        }
#pragma unroll
        for (int nt = 0; nt < 2; ++nt) {
            const int o = wnt * 32 + nt * 16 + rbase;
            const bf16x8 bf = *reinterpret_cast<const bf16x8*>(
                &cwB[(size_t)(n * CC + o) * 384 + ks * 32 + g8]);
#pragma unroll
            for (int m = 0; m < 4; ++m)
                acc[m][nt] = __builtin_amdgcn_mfma_f32_16x16x32_bf16(a[m], bf, acc[m][nt], 0, 0, 0);
        }
    }

    f32x4 accr[4][2] = {};
    if constexpr (RES_MODE == 1) {
#pragma unroll
        for (int ks = 0; ks < 2; ++ks) {
            const int ib = ks * 32 + g8;
            bf16x8 a[4];
#pragma unroll
            for (int m = 0; m < 4; ++m) {
                const int rl = m * 16 + rbase;
                a[m] = *reinterpret_cast<const bf16x8*>(
                           &h0s[(rl * 64 + ib) ^ ((rl & 7) << 3)]);
            }
#pragma unroll
            for (int nt = 0; nt < 2; ++nt) {
                const int o = wnt * 32 + nt * 16 + rbase;
                const bf16x8 bf = *reinterpret_cast<const bf16x8*>(
                    &rwB[(size_t)(n * CC + o) * HIDC + ib]);
#pragma unroll
                for (int m = 0; m < 4; ++m)
                    accr[m][nt] = __builtin_amdgcn_mfma_f32_16x16x32_bf16(a[m], bf, accr[m][nt], 0, 0, 0);
            }
        }
    }

    __syncthreads();  // xin reads done; reuse as result staging

    const int rrow = (lane >> 4) * 4;
#pragma unroll
    for (int nt = 0; nt < 2; ++nt) {
        const int o  = wnt * 32 + nt * 16 + rbase;
        const int ch = n * CC + o;
        const float s2 = bn2g[ch] * RSQ, bb2 = bn2b[ch], cbo = cb[ch];
        float rs = 0.f, rsh = 0.f, rbc = 0.f;
        if constexpr (RES_MODE == 1) { rs = rg[ch] * RSQ; rsh = rbb[ch]; rbc = rb[ch]; }
#pragma unroll
        for (int m = 0; m < 4; ++m) {
#pragma unroll
            for (int q = 0; q < 4; ++q) {
                const int r = m * 16 + rrow + q;
                float v = fmaxf(fmaf(acc[m][nt][q] + cbo, s2, bb2), 0.f);
                if constexpr (RES_MODE == 1) v += fmaf(accr[m][nt][q] + rbc, rs, rsh);
                xin[(r * 128 + o) ^ ((r & 7) << 3)] = f2bf(v);
            }
        }
    }
    __syncthreads();

    float pacc[8] = {};
    for (int c = tid; c < 64 * 16; c += 256) {
        const int r = c >> 4, s8 = c & 15;
        uint4 v = *reinterpret_cast<const uint4*>(
            &xin[(r * 128 + s8 * 8) ^ ((r & 7) << 3)]);
        const size_t oi = (((size_t)b * TNUM + t0 + r) * NJ + n) * CC + s8 * 8;
        if constexpr (RES_MODE == 0) {
            float f[8], g[8];
            unpack8(v, f);
            unpack8(*reinterpret_cast<const uint4*>(&OUT[oi]), g);
#pragma unroll
            for (int j = 0; j < 8; ++j) f[j] += g[j];
            if constexpr (POOL == 1) {
#pragma unroll
                for (int j = 0; j < 8; ++j) pacc[j] += f[j];
            } else {
                *reinterpret_cast<uint4*>(&OUT[oi]) = pack8(f);
            }
        } else {
            *reinterpret_cast<uint4*>(&OUT[oi]) = v;
        }
    }

    if constexpr (POOL == 1) {
        __syncthreads();
        float* fred = reinterpret_cast<float*>(xin);
#pragma unroll
        for (int j = 0; j < 8; ++j) fred[tid * 8 + j] = pacc[j];
        __syncthreads();
        if (tid < 128) {
            const int s8 = tid >> 3, j = tid & 7;
            float s = 0.f;
#pragma unroll
            for (int k = 0; k < 16; ++k) s += fred[(s8 + 16 * k) * 8 + j];
            atomicAdd(&pooled[((size_t)b * NJ + n) * CC + s8 * 8 + j], s * (1.0f / TNUM));
        }
    }
}

// MLP head: 2176 -> 128 -> 64 -> 1, relu/relu/sigmoid
__global__ __launch_bounds__(128) void k_mlp(const float* __restrict__ P,
        const float* __restrict__ w1, const float* __restrict__ b1,
        const float* __restrict__ w2, const float* __restrict__ b2,
        const float* __restrict__ w3, const float* __restrict__ b3,
        float* __restrict__ out) {
    __shared__ float h1[128];
    __shared__ float h2[64];
    const int b = blockIdx.x, tid = threadIdx.x;
    const float* pr = P + (size_t)b * (NJ * CC);
    float acc = b1[tid];
    for (int i = 0; i < NJ * CC; ++i) acc = fmaf(pr[i], w1[i * 128 + tid], acc);
    h1[tid] = fmaxf(acc, 0.f);
    __syncthreads();
    if (tid < 64) {
        float a2 = b2[tid];
#pragma unroll 4
        for (int i = 0; i < 128; ++i) a2 = fmaf(h1[i], w2[i * 64 + tid], a2);
        h2[tid] = fmaxf(a2, 0.f);
    }
    __syncthreads();
    if (tid == 0) {
        float a3 = b3[0];
#pragma unroll 4
        for (int i = 0; i < 64; ++i) a3 = fmaf(h2[i], w3[i], a3);
        out[b] = 1.f / (1.f + expf(-a3));
    }
}

extern "C" void kernel_launch(void* const* d_in, const int* in_sizes, int n_in,
                              void* d_out, int out_size, void* d_ws, size_t ws_size,
                              hipStream_t stream) {
    const float* x    = (const float*)d_in[0];
    const float* w_in = (const float*)d_in[1];
    const float* b_in = (const float*)d_in[2];
    const float *gw[3], *gb[3], *bn1g[3], *bn1b[3], *cw[3], *cb[3], *bn2g[3], *bn2b[3];
    for (int l = 0; l < 3; ++l) {
        const int base = 3 + l * 8;
        gw[l]   = (const float*)d_in[base + 0];
        gb[l]   = (const float*)d_in[base + 1];
        bn1g[l] = (const float*)d_in[base + 2];
        bn1b[l] = (const float*)d_in[base + 3];
        cw[l]   = (const float*)d_in[base + 4];
        cb[l]   = (const float*)d_in[base + 5];
        bn2g[l] = (const float*)d_in[base + 6];
        bn2b[l] = (const float*)d_in[base + 7];
    }
    const float* rw0  = (const float*)d_in[27];
    const float* rb0  = (const float*)d_in[28];
    const float* rg0  = (const float*)d_in[29];
    const float* rbb0 = (const float*)d_in[30];
    const float* w1   = (const float*)d_in[31];
    const float* b1   = (const float*)d_in[32];
    const float* w2   = (const float*)d_in[33];
    const float* b2   = (const float*)d_in[34];
    const float* w3   = (const float*)d_in[35];
    const float* b3   = (const float*)d_in[36];

    const size_t CWB    = (size_t)NJ * CC * 3 * CC;
    const size_t RWB    = (size_t)NJ * CC * HIDC;
    const size_t GWB128 = (size_t)CC * CC;
    const size_t GWB64  = (size_t)CC * HIDC;
    const size_t ACT_B  = (size_t)TNUM * NJ * CC;
    const size_t POOLED = (size_t)BNUM * NJ * CC;
    const size_t fixedB = (3 * CWB + RWB + 2 * GWB128 + GWB64) * sizeof(unsigned short)
                        + POOLED * sizeof(float);

    int chunk = 0;
    for (int c = BNUM; c >= 1; c >>= 1) {
        const size_t need = fixedB + 2 * (size_t)c * ACT_B * sizeof(unsigned short);
        if (need <= ws_size) { chunk = c; break; }
    }
    if (chunk == 0) {
        k_fallback<<<1, 64, 0, stream>>>((float*)d_out);
        return;
    }

    unsigned short* cwB0 = (unsigned short*)d_ws;
    unsigned short* cwB1 = cwB0 + CWB;
    unsigned short* cwB2 = cwB1 + CWB;
    unsigned short* rwB  = cwB2 + CWB;
    unsigned short* gwB0 = rwB + RWB;
    unsigned short* gwB1 = gwB0 + GWB64;
    unsigned short* gwB2 = gwB1 + GWB128;
    float* pooled = (float*)(gwB2 + GWB128);
    unsigned short* bufA = (unsigned short*)(pooled + POOLED);
    unsigned short* bufB = bufA + (size_t)chunk * ACT_B;

    dim3 pgrid((int)((CWB + 255) / 256), 3, 1);
    k_prep_cwB<<<pgrid, 256, 0, stream>>>(cw[0], cw[1], cw[2], cwB0);
    const size_t MISC = RWB + GWB64 + 2 * GWB128;
    k_prep_misc<<<(int)((MISC + 255) / 256), 256, 0, stream>>>(
        rw0, gw[0], gw[1], gw[2], rwB, gwB0, gwB1, gwB2);
    k_zero<<<(int)((POOLED + 255) / 256), 256, 0, stream>>>(pooled, (int)POOLED);

    for (int b0 = 0; b0 < BNUM; b0 += chunk) {
        const float* xc = x + (size_t)b0 * TNUM * NJ * 3;
        const int GB = chunk * TNUM / 16;
        const dim3 tgrid(TNUM / 64, NJ, chunk);
        float* pc = pooled + (size_t)b0 * NJ * CC;

        k_gcn0_mfma<<<GB, 256, 0, stream>>>(xc, w_in, b_in, gwB0,
                                            gb[0], bn1g[0], bn1b[0], bufA);
        k_tconv_mfma<1, 0><<<tgrid, 256, 0, stream>>>(bufA, cwB0, cb[0], bn2g[0], bn2b[0],
                                                      xc, w_in, b_in, rwB, rb0, rg0, rbb0,
                                                      bufB, nullptr);
        k_gcn_mfma<<<GB, 256, 0, stream>>>(bufB, gwB1, gb[1], bn1g[1], bn1b[1], bufA);
        k_tconv_mfma<0, 0><<<tgrid, 256, 0, stream>>>(bufA, cwB1, cb[1], bn2g[1], bn2b[1],
                                                      nullptr, w_in, b_in, nullptr, nullptr, nullptr, nullptr,
                                                      bufB, nullptr);
        k_gcn_mfma<<<GB, 256, 0, stream>>>(bufB, gwB2, gb[2], bn1g[2], bn1b[2], bufA);
        k_tconv_mfma<0, 1><<<tgrid, 256, 0, stream>>>(bufA, cwB2, cb[2], bn2g[2], bn2b[2],
                                                      nullptr, w_in, b_in, nullptr, nullptr, nullptr, nullptr,
                                                      bufB, pc);
    }

    k_mlp<<<BNUM, 128, 0, stream>>>(pooled, w1, b1, w2, b2, w3, b3, (float*)d_out);
}